// Round 8
// baseline (351.941 us; speedup 1.0000x reference)
//
#include <hip/hip_runtime.h>
#include <math.h>

#define NV 720
#define NU 736
#define NUP 768      // padded Q row stride (bins 736..767 never gathered)
#define NXY 512
#define GRID 1024    // 4 blocks/CU x 256 CU — exactly co-resident (128-VGPR cap, 24.6KB LDS)

// ---- software grid barrier (R24) ------------------------------------------------------
// R22/R23 failed with IDENTICAL absmax (3.1738e-2 = max|ref|) -> hipLaunchCooperativeKernel
// never executed (error ignored; harness memset left out=0). Replace with a plain launch
// + workspace spin barrier. Co-residency: __launch_bounds__(256,4) -> <=128 VGPR -> 16
// waves/CU (m69) = 4 blocks/CU; LDS 24.6KB <= 40KB. bar = {cnt0,flag0,cnt1,flag1}, zeroed
// by hipMemsetAsync each launch. Agent-scope atomics + threadfence_system on both sides
// (XCD L2 writeback/invalidate). clock64 timeout: degrade to wrong-answer, never hang.
__device__ __forceinline__ void gsync(int* bar, int slot, int tid) {
    __syncthreads();
    if (tid == 0) {
        __threadfence_system();                       // release prior global writes
        int* cnt = bar + 2 * slot;
        int* flag = bar + 2 * slot + 1;
        if (__hip_atomic_fetch_add(cnt, 1, __ATOMIC_ACQ_REL, __HIP_MEMORY_SCOPE_AGENT)
            == GRID - 1) {
            __hip_atomic_store(flag, 1, __ATOMIC_RELEASE, __HIP_MEMORY_SCOPE_AGENT);
        } else {
            long long t0 = clock64();
            while (__hip_atomic_load(flag, __ATOMIC_ACQUIRE, __HIP_MEMORY_SCOPE_AGENT) == 0) {
                __builtin_amdgcn_s_sleep(8);
                if (clock64() - t0 > 100000000LL) break;   // ~40ms escape hatch
            }
        }
        __threadfence_system();                       // acquire: drop stale lines
    }
    __syncthreads();
}

__global__ __launch_bounds__(256, 4) void fused_kernel(const float* __restrict__ sino,
                                                       float* __restrict__ Q,
                                                       float4* __restrict__ trig,
                                                       float* __restrict__ out,
                                                       int* __restrict__ bar) {
    __shared__ __align__(16) char smem[24576];   // union: filter {s4,wco,part} | bp {win}
    const int bid = blockIdx.x;
    const int tid = threadIdx.x;
    const int gid = bid * 256 + tid;

    // ================= phase 0: zero out + trig =================
    out[gid] = 0.0f;                              // 1024*256 == 512*512 exactly
    if (gid < NV) {
        float beta = (float)((double)gid * (2.0 * M_PI / 720.0));
        float cb = cosf(beta), sb = sinf(beta);
        const float K = (float)(1085.6 / 1.2858);   // DSD/DU
        trig[gid] = make_float4(cb * K, sb * K, cb, sb);
    }
    gsync(bar, 0, tid);

    // ================= phase 1: self-staged Ram-Lak filter (blocks 0..719) ==============
    if (bid < 720) {
        float (*s4)[368][4] = (float(*)[368][4])smem;         // [par][m][view] 11776 B
        float* wco = (float*)(smem + 11776);                  // 736 floats    2944 B
        float (*part)[96] = (float(*)[96])(smem + 14720);     // [8 comp][96]  3072 B
        const int q = bid & 3;                    // output quadrant: r = q
        const int vb = bid >> 2;
        const int v0 = vb * 4;
        const int tz = tid >> 7;                  // tap chunk {0,1}: 184 taps each
        const int J0 = tid & 127;                 // output slot; active if < 92

        const float DSD2 = (float)(1085.6 * 1085.6);
        for (int i = tid; i < 4 * NU; i += 256) { // stage 4 views, coalesced in u
            const int vv = i / NU, u = i - vv * NU;
            float us = ((float)u - 367.5f) * 1.2858f;
            float cw = 1085.6f / sqrtf(DSD2 + us * us);
            s4[u & 1][u >> 1][vv] = sino[(v0 + vv) * NU + u] * cw;
        }
        for (int i = tid; i < 736; i += 256) {
            double n = (double)(2 * i - 735);
            double a = M_PI * n * 1.2858;
            wco[i] = (float)(-1.0 / (a * a));
        }
        __syncthreads();

        const int m0 = 184 * tz;
        float a00 = 0.f, a01 = 0.f, a02 = 0.f, a03 = 0.f;   // pj=0, views 0..3
        float a10 = 0.f, a11 = 0.f, a12 = 0.f, a13 = 0.f;   // pj=1, views 0..3
        const int J0c = min(J0, 91);              // lanes J0>=92: throwaway, in-bounds
        const int y0 = J0c + 367 + 92 * q;        // weight idx y = y0 - m (pj=0), +1 (pj=1)
        const float* wp = &wco[y0 - m0];

        #pragma unroll 4
        for (int mm = 0; mm < 184; ++mm) {        // m = m0+mm ascending
            const int m = m0 + mm;
            const float w0 = wp[-mm];             // pj=0 }  one ds_read2_b32
            const float w1 = wp[1 - mm];          // pj=1 }
            const float4 sv1 = *(const float4*)&s4[1][m][0];   // parity 1 (for pj=0)
            const float4 sv0 = *(const float4*)&s4[0][m][0];   // parity 0 (for pj=1)
            a00 = fmaf(w0, sv1.x, a00); a01 = fmaf(w0, sv1.y, a01);
            a02 = fmaf(w0, sv1.z, a02); a03 = fmaf(w0, sv1.w, a03);
            a10 = fmaf(w1, sv0.x, a10); a11 = fmaf(w1, sv0.y, a11);
            a12 = fmaf(w1, sv0.z, a12); a13 = fmaf(w1, sv0.w, a13);
        }

        if (tz == 1 && J0 < 92) {
            part[0][J0] = a00; part[1][J0] = a01; part[2][J0] = a02; part[3][J0] = a03;
            part[4][J0] = a10; part[5][J0] = a11; part[6][J0] = a12; part[7][J0] = a13;
        }
        __syncthreads();

        if (tz == 0 && J0 < 92) {
            a00 += part[0][J0]; a01 += part[1][J0];   // chunk1 after chunk0 (ascending)
            a02 += part[2][J0]; a03 += part[3][J0];
            a10 += part[4][J0]; a11 += part[5][J0];
            a12 += part[6][J0]; a13 += part[7][J0];
            const float H0 = (float)(1.0 / (4.0 * 1.2858 * 1.2858));
            const int mc = J0 + 92 * q;               // center tap pair index
            const float4 c0 = *(const float4*)&s4[0][mc][0];   // u = 2mc   (pj=0)
            const float4 c1 = *(const float4*)&s4[1][mc][0];   // u = 2mc+1 (pj=1)
            a00 = fmaf(H0, c0.x, a00); a01 = fmaf(H0, c0.y, a01);
            a02 = fmaf(H0, c0.z, a02); a03 = fmaf(H0, c0.w, a03);
            a10 = fmaf(H0, c1.x, a10); a11 = fmaf(H0, c1.y, a11);
            a12 = fmaf(H0, c1.z, a12); a13 = fmaf(H0, c1.w, a13);
            const int j0i = 2 * mc;
            const float DU = 1.2858f;
            *(float2*)&Q[(v0 + 0) * NUP + j0i] = make_float2(a00 * DU, a10 * DU);
            *(float2*)&Q[(v0 + 1) * NUP + j0i] = make_float2(a01 * DU, a11 * DU);
            *(float2*)&Q[(v0 + 2) * NUP + j0i] = make_float2(a02 * DU, a12 * DU);
            *(float2*)&Q[(v0 + 3) * NUP + j0i] = make_float2(a03 * DU, a13 * DU);
        }
    }
    gsync(bar, 1, tid);

    // ================= phase 2: backprojection (R15 body, 4 tiles/block) ================
    float (*win)[4][NUP] = (float(*)[4][NUP])smem;       // 24 KB double buffer
    const int cc = bid & 15;                  // view chunk (same for all 4 tiles)
    const int t = tid;
    const int w = t >> 6;
    const int l = t & 63;
    const float dx = 400.0f / 512.0f;         // 0.78125 exact
    const float Kc = (float)(1085.6 / 1.2858);
    const int nk = (cc < 4) ? 12 : 11;        // ceil((180-cc)/16)

    #pragma unroll 1
    for (int ti = 0; ti < 4; ++ti) {
        const int blk = (bid >> 4) + ti * 64; // b = bid + ti*1024 -> blk in [0,256)
        const int bx = blk >> 4;
        const int by = blk & 15;
        const int iq = (bx << 4) + ((w >> 1) << 3) + (l >> 3);   // [0,256)
        const int jq = (by << 4) + ((w & 1) << 3) + (l & 7);     // [0,256)
        const float X = ((float)iq - 255.5f) * dx;   // < 0
        const float Y = ((float)jq - 255.5f) * dx;   // < 0
        float acc0 = 0.0f, acc1 = 0.0f, acc2 = 0.0f, acc3 = 0.0f;
        const bool inr = fmaf(X, X, Y * Y) <= 236.5f * 236.5f;
        const bool myint = __all(inr);

        const float* rowp = Q + (size_t)(cc + 180 * w) * NUP;   // wave w stages row w
        const float4* tvp = trig + cc;

        __syncthreads();                      // prior tile's reads done before overwrite
        #pragma unroll
        for (int ch = 0; ch < 3; ++ch)
            __builtin_amdgcn_global_load_lds(
                (const __attribute__((address_space(1))) void*)(rowp + ch * 256 + l * 4),
                (__attribute__((address_space(3))) void*)&win[0][w][ch * 256],
                16, 0, 0);

        for (int it = 0; it < nk; ++it) {
            __syncthreads();                  // win[it&1] staged; prior reads of it^1 done
            if (it + 1 < nk) {
                const float* rn = rowp + 16 * NUP;
                #pragma unroll
                for (int ch = 0; ch < 3; ++ch)
                    __builtin_amdgcn_global_load_lds(
                        (const __attribute__((address_space(1))) void*)(rn + ch * 256 + l * 4),
                        (__attribute__((address_space(3))) void*)&win[(it + 1) & 1][w][ch * 256],
                        16, 0, 0);
            }
            const float* winf = &win[it & 1][0][0];

            if (myint) {
                // ---- interior: symmetric geometry (R10-proven), ds_read2 gathers -----
                const float4 tv = tvp[0];                     // cb = tv.z, sb = tv.w
                float a = fmaf(tv.z, X, tv.w * Y);            // t0
                float bb = fmaf(tv.z, Y, -tv.w * X);          // s0
                float aK = a * Kc, bK = bb * Kc;
                float D0 = 595.0f - bb, D1 = 595.0f + a, D2 = 595.0f + bb, D3 = 595.0f - a;
                float r0 = __builtin_amdgcn_rcpf(D0);
                float r1 = __builtin_amdgcn_rcpf(D1);
                float r2 = __builtin_amdgcn_rcpf(D2);
                float r3 = __builtin_amdgcn_rcpf(D3);
                float fi0 = fmaf(aK,  r0, 367.5f);
                float fi1 = fmaf(bK,  r1, 367.5f);
                float fi2 = fmaf(-aK, r2, 367.5f);
                float fi3 = fmaf(-bK, r3, 367.5f);
                int im[4] = {(int)fi0, (int)fi1, (int)fi2, (int)fi3};  // in [1,733]
                float ff[4] = {__builtin_amdgcn_fractf(fi0), __builtin_amdgcn_fractf(fi1),
                               __builtin_amdgcn_fractf(fi2), __builtin_amdgcn_fractf(fi3)};
                float gg[4] = {r0 * r0, r1 * r1, r2 * r2, r3 * r3};
                float* accp[4] = {&acc0, &acc1, &acc2, &acc3};
                #pragma unroll
                for (int m = 0; m < 4; ++m) {
                    #pragma unroll
                    for (int k = 0; k < 4; ++k) {
                        const float* p = winf + (k * NUP + im[m]);
                        float q0 = p[0];                      // ds_read2_b32 (fused pair)
                        float q1 = p[1];
                        float val = fmaf(ff[m], q1 - q0, q0);
                        *accp[(m - k) & 3] = fmaf(gg[m], val, *accp[(m - k) & 3]);
                    }
                }
            } else {
                // ---- exterior: R3-exact chains/gates per pixel, staged ds_read2 ------
                const float4 tvs[4] = {tvp[0], tvp[180], tvp[360], tvp[540]};
                const float pX[4] = {X, Y, -X, -Y};
                const float pY[4] = {Y, -X, -Y, X};
                float* accp[4] = {&acc0, &acc1, &acc2, &acc3};
                #pragma unroll
                for (int j = 0; j < 4; ++j) {
                    float Xm = pX[j], Ym = pY[j];
                    #pragma unroll
                    for (int k = 0; k < 4; ++k) {
                        const float4 tv = tvs[k];
                        float t2 = fmaf(tv.x, Xm, tv.y * Ym);               // R3-exact
                        float D  = fmaf(tv.w, Xm, fmaf(tv.z, -Ym, 595.0f)); // R3-exact
                        float rD = __builtin_amdgcn_rcpf(D);
                        float fidx = fmaf(t2, rD, 367.5f);
                        int i0c = min(max((int)fidx, 0), NU - 2);           // v_med3_i32
                        float f = __builtin_amdgcn_fractf(fidx);
                        const float* p = winf + (k * NUP + i0c);
                        float q0 = p[0];                                    // ds_read2_b32
                        float q1 = p[1];
                        float val = fmaf(f, q1 - q0, q0);
                        float cen = fidx - 367.5f;                          // R3-exact gate
                        float g = (__builtin_fabsf(cen) <= 367.5f) ? rD * rD : 0.0f;
                        *accp[j] = fmaf(g, val, *accp[j]);
                    }
                }
            }
            rowp += 16 * NUP;
            tvp += 16;
        }
        const float SC = (float)(595.0 * 595.0 * 0.5 * (2.0 * M_PI / 720.0));
        const int ir = 511 - iq, jr = 511 - jq;
        unsafeAtomicAdd(&out[iq * NXY + jq], acc0 * SC);   // P0 = (iq, jq)
        unsafeAtomicAdd(&out[jq * NXY + ir], acc1 * SC);   // P1 = (jq, 511-iq)
        unsafeAtomicAdd(&out[ir * NXY + jr], acc2 * SC);   // P2 = (511-iq, 511-jq)
        unsafeAtomicAdd(&out[jr * NXY + iq], acc3 * SC);   // P3 = (511-jq, iq)
    }
}

extern "C" void kernel_launch(void* const* d_in, const int* in_sizes, int n_in,
                              void* d_out, int out_size, void* d_ws, size_t ws_size,
                              hipStream_t stream) {
    const float* sino = (const float*)d_in[0];
    float* out = (float*)d_out;
    float* Q = (float*)d_ws;                                // 720*768*4 = 2,211,840 B
    float4* trig = (float4*)((char*)d_ws + (size_t)NV * NUP * sizeof(float));
    int* bar = (int*)((char*)trig + (size_t)NV * sizeof(float4));   // 16 B barrier state

    hipMemsetAsync(bar, 0, 16, stream);                     // zero {cnt0,flag0,cnt1,flag1}
    fused_kernel<<<GRID, 256, 0, stream>>>(sino, Q, trig, out, bar);
}

// Round 9
// 112.965 us; speedup vs baseline: 3.1155x; 3.1155x over previous
//
#include <hip/hip_runtime.h>
#include <math.h>

#define NV 720
#define NU 736
#define NUP 768      // padded Q row stride (bins 736..767 never gathered)
#define NXY 512

// ---------------- Stage 1+2 (R25): merged-parity Ram-Lak filter, 720 blocks ------------
// R24 lessons: (a) fused+grid-barrier = +235us of L2 wb/inv coherence overhead -> 2-dispatch
// structure is optimal; (b) harness fixed overhead ~40us; (c) filter compute is only ~12us
// (VALU accounting) -> its ~17us standalone time is CU imbalance (R18: 360 blocks = 2.0x).
// R25 filter: R24's HW-validated merged-parity inner body (2x b128 broadcast + 1 lane-
// varying ds_read2 per 8 FMAs), re-chunked to R18's 4x92 association -> Q BIT-IDENTICAL
// to R18 (ascending m, chunks ascending, center last, *DU last). Grid 720 = 180 vgroups
// x 4 r-quadrants, 512 thr (8 waves): 3 blocks/CU, imbalance 1.07, 24 waves/CU.
__global__ __launch_bounds__(512) void filter_kernel(const float* __restrict__ sino,
                                                     float* __restrict__ Q,
                                                     float4* __restrict__ trig,
                                                     float* __restrict__ out_zero) {
    __shared__ float s4[2][368][4];   // [parity][m][view]  11776 B
    __shared__ float wco[736];        //                     2944 B
    __shared__ float part[3][128][8]; // chunk partials     12288 B  (27 KB total)
    const int bx = blockIdx.x;
    const int q = bx & 3;             // output quadrant: r = q
    const int vb = bx >> 2;
    const int v0 = vb * 4;
    const int tid = threadIdx.x;      // [0,512)
    const int tz = tid >> 7;          // tap chunk [0,4): taps [92*tz, 92*tz+92)
    const int J0 = tid & 127;         // output slot; outputs if < 92

    // zero the atomic target (replaces the hipMemsetAsync dispatch; bp launches after)
    for (int i = bx * 512 + tid; i < NXY * NXY; i += 720 * 512)
        out_zero[i] = 0.0f;

    if (q == 0 && tid < 4) {
        int v = v0 + tid;
        float beta = (float)((double)v * (2.0 * M_PI / 720.0));
        float cb = cosf(beta), sb = sinf(beta);
        const float K = (float)(1085.6 / 1.2858);   // DSD/DU
        trig[v] = make_float4(cb * K, sb * K, cb, sb);
    }
    const float DSD2 = (float)(1085.6 * 1085.6);
    for (int i = tid; i < 4 * NU; i += 512) {   // stage 4 views, coalesced in u
        const int vv = i / NU, u = i - vv * NU;
        float us = ((float)u - 367.5f) * 1.2858f;
        float cw = 1085.6f / sqrtf(DSD2 + us * us);
        s4[u & 1][u >> 1][vv] = sino[(v0 + vv) * NU + u] * cw;
    }
    for (int i = tid; i < 736; i += 512) {
        double n = (double)(2 * i - 735);
        double a = M_PI * n * 1.2858;
        wco[i] = (float)(-1.0 / (a * a));
    }
    __syncthreads();

    const int m0 = 92 * tz;
    float a00 = 0.f, a01 = 0.f, a02 = 0.f, a03 = 0.f;   // pj=0, views 0..3
    float a10 = 0.f, a11 = 0.f, a12 = 0.f, a13 = 0.f;   // pj=1, views 0..3
    const int J0c = min(J0, 91);              // lanes J0>=92: throwaway, in-bounds
    const int y0 = J0c + 367 + 92 * q;        // weight idx y = y0 - m (pj=0), +1 (pj=1)
    const float* wp = &wco[y0 - m0];

    #pragma unroll 4
    for (int mm = 0; mm < 92; ++mm) {         // m = m0+mm ascending (R18 order)
        const int m = m0 + mm;
        const float w0 = wp[-mm];             // pj=0 }  one ds_read2_b32 (lane-varying)
        const float w1 = wp[1 - mm];          // pj=1 }
        const float4 sv1 = *(const float4*)&s4[1][m][0];   // broadcast (uniform addr)
        const float4 sv0 = *(const float4*)&s4[0][m][0];   // broadcast
        a00 = fmaf(w0, sv1.x, a00); a01 = fmaf(w0, sv1.y, a01);
        a02 = fmaf(w0, sv1.z, a02); a03 = fmaf(w0, sv1.w, a03);
        a10 = fmaf(w1, sv0.x, a10); a11 = fmaf(w1, sv0.y, a11);
        a12 = fmaf(w1, sv0.z, a12); a13 = fmaf(w1, sv0.w, a13);
    }

    if (tz != 0 && J0 < 92) {
        *(float4*)&part[tz - 1][J0][0] = make_float4(a00, a01, a02, a03);
        *(float4*)&part[tz - 1][J0][4] = make_float4(a10, a11, a12, a13);
    }
    __syncthreads();

    if (tz == 0 && J0 < 92) {
        #pragma unroll
        for (int g = 0; g < 3; ++g) {         // chunks ascending (R18 order)
            const float4 p0 = *(const float4*)&part[g][J0][0];
            const float4 p1 = *(const float4*)&part[g][J0][4];
            a00 += p0.x; a01 += p0.y; a02 += p0.z; a03 += p0.w;
            a10 += p1.x; a11 += p1.y; a12 += p1.z; a13 += p1.w;
        }
        const float H0 = (float)(1.0 / (4.0 * 1.2858 * 1.2858));
        const int mc = J0 + 92 * q;           // center tap pair index: u = j
        const float4 c0 = *(const float4*)&s4[0][mc][0];   // u = 2mc   (pj=0)
        const float4 c1 = *(const float4*)&s4[1][mc][0];   // u = 2mc+1 (pj=1)
        a00 = fmaf(H0, c0.x, a00); a01 = fmaf(H0, c0.y, a01);
        a02 = fmaf(H0, c0.z, a02); a03 = fmaf(H0, c0.w, a03);
        a10 = fmaf(H0, c1.x, a10); a11 = fmaf(H0, c1.y, a11);
        a12 = fmaf(H0, c1.z, a12); a13 = fmaf(H0, c1.w, a13);
        const int j0i = 2 * mc;
        const float DU = 1.2858f;
        *(float2*)&Q[(v0 + 0) * NUP + j0i] = make_float2(a00 * DU, a10 * DU);
        *(float2*)&Q[(v0 + 1) * NUP + j0i] = make_float2(a01 * DU, a11 * DU);
        *(float2*)&Q[(v0 + 2) * NUP + j0i] = make_float2(a02 * DU, a12 * DU);
        *(float2*)&Q[(v0 + 3) * NUP + j0i] = make_float2(a03 * DU, a13 * DU);
    }
}

// ---------------- Stage 3: backprojection — R15 body + T5 setprio ----------------------
// bp is 3-4 independent blocks/CU at different pipeline phases (attn-like regime where
// setprio measured +4-7%, m191 — not the lockstep-GEMM null). setprio(1) wraps the
// DS-gather+FMA cluster; staging/barrier at prio 0. Pure scheduling hint, no numerics.
// R16 lesson: no address-dependent VMEM in the hot loop. R14: DS-crossbar binding;
// ds_read2 per bilinear gather. R15: dbuf. No gate-chain reassociation (R4).
__global__ __launch_bounds__(256) void bp_kernel(const float* __restrict__ Q,
                                                 const float4* __restrict__ trig,
                                                 float* __restrict__ out) {
    __shared__ float win[2][4][NUP];          // 24 KB double buffer
    const int b = blockIdx.x;
    const int c = b & 15;                     // view chunk: base views {c, c+16, ...}
    const int blk = b >> 4;                   // 256 quadrant blocks of 16x16
    const int bx = blk >> 4;
    const int by = blk & 15;
    const int t = threadIdx.x;
    const int w = t >> 6;
    const int l = t & 63;
    const int iq = (bx << 4) + ((w >> 1) << 3) + (l >> 3);   // [0,256)
    const int jq = (by << 4) + ((w & 1) << 3) + (l & 7);     // [0,256)

    const float dx = 400.0f / 512.0f;         // 0.78125 exact
    const float X = ((float)iq - 255.5f) * dx;   // < 0
    const float Y = ((float)jq - 255.5f) * dx;   // < 0
    const float Kc = (float)(1085.6 / 1.2858);

    float acc0 = 0.0f, acc1 = 0.0f, acc2 = 0.0f, acc3 = 0.0f;
    const bool inr = fmaf(X, X, Y * Y) <= 236.5f * 236.5f;
    const bool myint = __all(inr);

    const int nk = (c < 4) ? 12 : 11;         // ceil((180-c)/16)
    const float* rowp = Q + (size_t)(c + 180 * w) * NUP;   // wave w stages row w
    const float4* tvp = trig + c;

    // preload iter 0 into buffer 0
    #pragma unroll
    for (int ch = 0; ch < 3; ++ch)
        __builtin_amdgcn_global_load_lds(
            (const __attribute__((address_space(1))) void*)(rowp + ch * 256 + l * 4),
            (__attribute__((address_space(3))) void*)&win[0][w][ch * 256],
            16, 0, 0);

    for (int it = 0; it < nk; ++it) {
        __syncthreads();                      // win[it&1] staged; prior reads of it^1 done
        if (it + 1 < nk) {
            const float* rn = rowp + 16 * NUP;
            #pragma unroll
            for (int ch = 0; ch < 3; ++ch)
                __builtin_amdgcn_global_load_lds(
                    (const __attribute__((address_space(1))) void*)(rn + ch * 256 + l * 4),
                    (__attribute__((address_space(3))) void*)&win[(it + 1) & 1][w][ch * 256],
                    16, 0, 0);
        }
        const float* winf = &win[it & 1][0][0];

        __builtin_amdgcn_s_setprio(1);        // T5: favor the gather+FMA cluster
        if (myint) {
            // ---- interior: symmetric geometry (R10-proven), ds_read2 gathers ---------
            const float4 tv = tvp[0];                     // cb = tv.z, sb = tv.w
            float a = fmaf(tv.z, X, tv.w * Y);            // t0
            float bb = fmaf(tv.z, Y, -tv.w * X);          // s0
            float aK = a * Kc, bK = bb * Kc;
            float D0 = 595.0f - bb, D1 = 595.0f + a, D2 = 595.0f + bb, D3 = 595.0f - a;
            float r0 = __builtin_amdgcn_rcpf(D0);
            float r1 = __builtin_amdgcn_rcpf(D1);
            float r2 = __builtin_amdgcn_rcpf(D2);
            float r3 = __builtin_amdgcn_rcpf(D3);
            float fi0 = fmaf(aK,  r0, 367.5f);
            float fi1 = fmaf(bK,  r1, 367.5f);
            float fi2 = fmaf(-aK, r2, 367.5f);
            float fi3 = fmaf(-bK, r3, 367.5f);
            int im[4] = {(int)fi0, (int)fi1, (int)fi2, (int)fi3};  // in [1,733]
            float ff[4] = {__builtin_amdgcn_fractf(fi0), __builtin_amdgcn_fractf(fi1),
                           __builtin_amdgcn_fractf(fi2), __builtin_amdgcn_fractf(fi3)};
            float gg[4] = {r0 * r0, r1 * r1, r2 * r2, r3 * r3};
            float* accp[4] = {&acc0, &acc1, &acc2, &acc3};
            #pragma unroll
            for (int m = 0; m < 4; ++m) {
                #pragma unroll
                for (int k = 0; k < 4; ++k) {
                    const float* p = winf + (k * NUP + im[m]);
                    float q0 = p[0];                      // ds_read2_b32 (fused pair)
                    float q1 = p[1];
                    float val = fmaf(ff[m], q1 - q0, q0);
                    *accp[(m - k) & 3] = fmaf(gg[m], val, *accp[(m - k) & 3]);
                }
            }
        } else {
            // ---- exterior: R3-exact chains/gates per pixel, staged ds_read2 fetch ----
            const float4 tvs[4] = {tvp[0], tvp[180], tvp[360], tvp[540]};
            const float pX[4] = {X, Y, -X, -Y};
            const float pY[4] = {Y, -X, -Y, X};
            float* accp[4] = {&acc0, &acc1, &acc2, &acc3};
            #pragma unroll
            for (int j = 0; j < 4; ++j) {
                float Xm = pX[j], Ym = pY[j];
                #pragma unroll
                for (int k = 0; k < 4; ++k) {
                    const float4 tv = tvs[k];
                    float t2 = fmaf(tv.x, Xm, tv.y * Ym);               // R3-exact
                    float D  = fmaf(tv.w, Xm, fmaf(tv.z, -Ym, 595.0f)); // R3-exact
                    float rD = __builtin_amdgcn_rcpf(D);
                    float fidx = fmaf(t2, rD, 367.5f);
                    int i0c = min(max((int)fidx, 0), NU - 2);           // v_med3_i32
                    float f = __builtin_amdgcn_fractf(fidx);
                    const float* p = winf + (k * NUP + i0c);
                    float q0 = p[0];                                    // ds_read2_b32
                    float q1 = p[1];
                    float val = fmaf(f, q1 - q0, q0);
                    float cen = fidx - 367.5f;                          // R3-exact gate
                    float g = (__builtin_fabsf(cen) <= 367.5f) ? rD * rD : 0.0f;
                    *accp[j] = fmaf(g, val, *accp[j]);
                }
            }
        }
        __builtin_amdgcn_s_setprio(0);
        rowp += 16 * NUP;
        tvp += 16;
    }
    const float SC = (float)(595.0 * 595.0 * 0.5 * (2.0 * M_PI / 720.0));
    const int ir = 511 - iq, jr = 511 - jq;
    unsafeAtomicAdd(&out[iq * NXY + jq], acc0 * SC);   // P0 = (iq, jq)
    unsafeAtomicAdd(&out[jq * NXY + ir], acc1 * SC);   // P1 = (jq, 511-iq)
    unsafeAtomicAdd(&out[ir * NXY + jr], acc2 * SC);   // P2 = (511-iq, 511-jq)
    unsafeAtomicAdd(&out[jr * NXY + iq], acc3 * SC);   // P3 = (511-jq, iq)
}

extern "C" void kernel_launch(void* const* d_in, const int* in_sizes, int n_in,
                              void* d_out, int out_size, void* d_ws, size_t ws_size,
                              hipStream_t stream) {
    const float* sino = (const float*)d_in[0];
    float* out = (float*)d_out;
    float* Q = (float*)d_ws;                                           // 720*768*4 = 2.21 MB
    float4* trig = (float4*)((char*)d_ws + (size_t)NV * NUP * sizeof(float)); // 16B-aligned

    filter_kernel<<<720, 512, 0, stream>>>(sino, Q, trig, out);        // also zeroes out
    bp_kernel<<<4096, 256, 0, stream>>>(Q, trig, out);
}

// Round 10
// 108.349 us; speedup vs baseline: 3.2482x; 1.0426x over previous
//
#include <hip/hip_runtime.h>
#include <math.h>

#define NV 720
#define NU 736
#define NUP 768      // padded detector stride (bins 736..767 never gathered)
#define NXY 512
// Qi layout (R26): Qi[v % 180][u in 0..767][v / 180]  -- one bp window (fixed v%180,
// all 4 v/180 groups) is 768*4 floats = 12 KB CONTIGUOUS. Row stride 3072 floats.

// ---------------- Stage 1+2 (R26): merged-parity Ram-Lak filter --------------------------
// Identical COMPUTE to R25 (Q values bit-identical to R18: ascending m, 4x92 chunks
// ascending, center last, *DU last). Only the STORE addressing changed: Qi interleaved
// layout so bp's window is contiguous and its gathers share one base per geometry.
// Grid 720 = 180 vgroups x 4 r-quadrants, 512 thr: imbalance 1.07, 24 waves/CU.
__global__ __launch_bounds__(512) void filter_kernel(const float* __restrict__ sino,
                                                     float* __restrict__ Qi,
                                                     float4* __restrict__ trig,
                                                     float* __restrict__ out_zero) {
    __shared__ float s4[2][368][4];   // [parity][m][view]  11776 B
    __shared__ float wco[736];        //                     2944 B
    __shared__ float part[3][128][8]; // chunk partials     12288 B  (27 KB total)
    const int bx = blockIdx.x;
    const int q = bx & 3;             // output quadrant: r = q
    const int vb = bx >> 2;
    const int v0 = vb * 4;
    const int tid = threadIdx.x;      // [0,512)
    const int tz = tid >> 7;          // tap chunk [0,4): taps [92*tz, 92*tz+92)
    const int J0 = tid & 127;         // output slot; outputs if < 92

    // zero the atomic target (replaces the hipMemsetAsync dispatch; bp launches after)
    for (int i = bx * 512 + tid; i < NXY * NXY; i += 720 * 512)
        out_zero[i] = 0.0f;

    if (q == 0 && tid < 4) {
        int v = v0 + tid;
        float beta = (float)((double)v * (2.0 * M_PI / 720.0));
        float cb = cosf(beta), sb = sinf(beta);
        const float K = (float)(1085.6 / 1.2858);   // DSD/DU
        trig[v] = make_float4(cb * K, sb * K, cb, sb);
    }
    const float DSD2 = (float)(1085.6 * 1085.6);
    for (int i = tid; i < 4 * NU; i += 512) {   // stage 4 views, coalesced in u
        const int vv = i / NU, u = i - vv * NU;
        float us = ((float)u - 367.5f) * 1.2858f;
        float cw = 1085.6f / sqrtf(DSD2 + us * us);
        s4[u & 1][u >> 1][vv] = sino[(v0 + vv) * NU + u] * cw;
    }
    for (int i = tid; i < 736; i += 512) {
        double n = (double)(2 * i - 735);
        double a = M_PI * n * 1.2858;
        wco[i] = (float)(-1.0 / (a * a));
    }
    __syncthreads();

    const int m0 = 92 * tz;
    float a00 = 0.f, a01 = 0.f, a02 = 0.f, a03 = 0.f;   // pj=0, views 0..3
    float a10 = 0.f, a11 = 0.f, a12 = 0.f, a13 = 0.f;   // pj=1, views 0..3
    const int J0c = min(J0, 91);              // lanes J0>=92: throwaway, in-bounds
    const int y0 = J0c + 367 + 92 * q;        // weight idx y = y0 - m (pj=0), +1 (pj=1)
    const float* wp = &wco[y0 - m0];

    #pragma unroll 4
    for (int mm = 0; mm < 92; ++mm) {         // m = m0+mm ascending (R18 order)
        const int m = m0 + mm;
        const float w0 = wp[-mm];             // pj=0 }  one ds_read2_b32 (lane-varying)
        const float w1 = wp[1 - mm];          // pj=1 }
        const float4 sv1 = *(const float4*)&s4[1][m][0];   // broadcast (uniform addr)
        const float4 sv0 = *(const float4*)&s4[0][m][0];   // broadcast
        a00 = fmaf(w0, sv1.x, a00); a01 = fmaf(w0, sv1.y, a01);
        a02 = fmaf(w0, sv1.z, a02); a03 = fmaf(w0, sv1.w, a03);
        a10 = fmaf(w1, sv0.x, a10); a11 = fmaf(w1, sv0.y, a11);
        a12 = fmaf(w1, sv0.z, a12); a13 = fmaf(w1, sv0.w, a13);
    }

    if (tz != 0 && J0 < 92) {
        *(float4*)&part[tz - 1][J0][0] = make_float4(a00, a01, a02, a03);
        *(float4*)&part[tz - 1][J0][4] = make_float4(a10, a11, a12, a13);
    }
    __syncthreads();

    if (tz == 0 && J0 < 92) {
        #pragma unroll
        for (int g = 0; g < 3; ++g) {         // chunks ascending (R18 order)
            const float4 p0 = *(const float4*)&part[g][J0][0];
            const float4 p1 = *(const float4*)&part[g][J0][4];
            a00 += p0.x; a01 += p0.y; a02 += p0.z; a03 += p0.w;
            a10 += p1.x; a11 += p1.y; a12 += p1.z; a13 += p1.w;
        }
        const float H0 = (float)(1.0 / (4.0 * 1.2858 * 1.2858));
        const int mc = J0 + 92 * q;           // center tap pair index: u = j
        const float4 c0 = *(const float4*)&s4[0][mc][0];   // u = 2mc   (pj=0)
        const float4 c1 = *(const float4*)&s4[1][mc][0];   // u = 2mc+1 (pj=1)
        a00 = fmaf(H0, c0.x, a00); a01 = fmaf(H0, c0.y, a01);
        a02 = fmaf(H0, c0.z, a02); a03 = fmaf(H0, c0.w, a03);
        a10 = fmaf(H0, c1.x, a10); a11 = fmaf(H0, c1.y, a11);
        a12 = fmaf(H0, c1.z, a12); a13 = fmaf(H0, c1.w, a13);
        const int j0i = 2 * mc;
        const float DU = 1.2858f;
        // interleaved store: Qi[(v%180)][j][v/180]; v = v0+vv (all 4 share v/180)
        const int v180 = v0 % 180;            // views v180..v180+3 (no wrap: v0%4==0)
        const int wq = v0 / 180;
        float* qr = Qi + (size_t)v180 * 3072 + wq;
        qr[0 * 3072 + 4 * j0i]       = a00 * DU;  qr[0 * 3072 + 4 * (j0i + 1)] = a10 * DU;
        qr[1 * 3072 + 4 * j0i]       = a01 * DU;  qr[1 * 3072 + 4 * (j0i + 1)] = a11 * DU;
        qr[2 * 3072 + 4 * j0i]       = a02 * DU;  qr[2 * 3072 + 4 * (j0i + 1)] = a12 * DU;
        qr[3 * 3072 + 4 * j0i]       = a03 * DU;  qr[3 * 3072 + 4 * (j0i + 1)] = a13 * DU;
    }
}

// ---------------- Stage 3: bp — R15 body + setprio (R25) + interleaved window (R26) ----
// R26: window = Qi[c+16it][*][*] is 12 KB contiguous; staged with the same 12
// global_load_lds calls (wave w covers floats [w*768, w*768+767]). Gathers: per geometry
// m, one base pm = winf + 4*im[m]; the 4 views are ds_read2_b32 at immediate offsets
// {k, k+4} -> saves ~12 VALU addr ops/iter (bp's longer pole: VALU 36us vs DS 29us).
// Banks: dword = im*4+k -> ~6 lanes/im broadcast; im+-8 alias = 2-way (free, m136).
// Lessons kept: no in-loop address-dependent VMEM (R16), ds_read2 per bilinear (R14),
// dbuf (R15), no gate-chain reassociation (R4), setprio around gather cluster (R25).
__global__ __launch_bounds__(256) void bp_kernel(const float* __restrict__ Qi,
                                                 const float4* __restrict__ trig,
                                                 float* __restrict__ out) {
    __shared__ float win[2][4][NUP];          // 24 KB double buffer ([buf] linear 3072 f)
    const int b = blockIdx.x;
    const int c = b & 15;                     // view chunk: base views {c, c+16, ...}
    const int blk = b >> 4;                   // 256 quadrant blocks of 16x16
    const int bx = blk >> 4;
    const int by = blk & 15;
    const int t = threadIdx.x;
    const int w = t >> 6;
    const int l = t & 63;
    const int iq = (bx << 4) + ((w >> 1) << 3) + (l >> 3);   // [0,256)
    const int jq = (by << 4) + ((w & 1) << 3) + (l & 7);     // [0,256)

    const float dx = 400.0f / 512.0f;         // 0.78125 exact
    const float X = ((float)iq - 255.5f) * dx;   // < 0
    const float Y = ((float)jq - 255.5f) * dx;   // < 0
    const float Kc = (float)(1085.6 / 1.2858);

    float acc0 = 0.0f, acc1 = 0.0f, acc2 = 0.0f, acc3 = 0.0f;
    const bool inr = fmaf(X, X, Y * Y) <= 236.5f * 236.5f;
    const bool myint = __all(inr);

    const int nk = (c < 4) ? 12 : 11;         // ceil((180-c)/16)
    const float* rowp = Qi + (size_t)c * 3072;             // window base (contiguous 12KB)
    const float4* tvp = trig + c;

    // preload iter 0 into buffer 0 (wave w stages floats [w*768, w*768+767])
    #pragma unroll
    for (int ch = 0; ch < 3; ++ch)
        __builtin_amdgcn_global_load_lds(
            (const __attribute__((address_space(1))) void*)(rowp + w * 768 + ch * 256 + l * 4),
            (__attribute__((address_space(3))) void*)&win[0][w][ch * 256],
            16, 0, 0);

    for (int it = 0; it < nk; ++it) {
        __syncthreads();                      // win[it&1] staged; prior reads of it^1 done
        if (it + 1 < nk) {
            const float* rn = rowp + 16 * 3072;
            #pragma unroll
            for (int ch = 0; ch < 3; ++ch)
                __builtin_amdgcn_global_load_lds(
                    (const __attribute__((address_space(1))) void*)(rn + w * 768 + ch * 256 + l * 4),
                    (__attribute__((address_space(3))) void*)&win[(it + 1) & 1][w][ch * 256],
                    16, 0, 0);
        }
        const float* winf = &win[it & 1][0][0];

        __builtin_amdgcn_s_setprio(1);        // T5: favor the gather+FMA cluster
        if (myint) {
            // ---- interior: symmetric geometry (R10-proven), shared-base ds_read2 -----
            const float4 tv = tvp[0];                     // cb = tv.z, sb = tv.w
            float a = fmaf(tv.z, X, tv.w * Y);            // t0
            float bb = fmaf(tv.z, Y, -tv.w * X);          // s0
            float aK = a * Kc, bK = bb * Kc;
            float D0 = 595.0f - bb, D1 = 595.0f + a, D2 = 595.0f + bb, D3 = 595.0f - a;
            float r0 = __builtin_amdgcn_rcpf(D0);
            float r1 = __builtin_amdgcn_rcpf(D1);
            float r2 = __builtin_amdgcn_rcpf(D2);
            float r3 = __builtin_amdgcn_rcpf(D3);
            float fi0 = fmaf(aK,  r0, 367.5f);
            float fi1 = fmaf(bK,  r1, 367.5f);
            float fi2 = fmaf(-aK, r2, 367.5f);
            float fi3 = fmaf(-bK, r3, 367.5f);
            int im[4] = {(int)fi0, (int)fi1, (int)fi2, (int)fi3};  // in [1,733]
            float ff[4] = {__builtin_amdgcn_fractf(fi0), __builtin_amdgcn_fractf(fi1),
                           __builtin_amdgcn_fractf(fi2), __builtin_amdgcn_fractf(fi3)};
            float gg[4] = {r0 * r0, r1 * r1, r2 * r2, r3 * r3};
            float* accp[4] = {&acc0, &acc1, &acc2, &acc3};
            #pragma unroll
            for (int m = 0; m < 4; ++m) {
                const float* pm = winf + 4 * im[m];       // ONE base per geometry
                #pragma unroll
                for (int k = 0; k < 4; ++k) {
                    float q0 = pm[k];                     // ds_read2 offset0:k
                    float q1 = pm[k + 4];                 //          offset1:k+4
                    float val = fmaf(ff[m], q1 - q0, q0);
                    *accp[(m - k) & 3] = fmaf(gg[m], val, *accp[(m - k) & 3]);
                }
            }
        } else {
            // ---- exterior: R3-exact chains/gates per pixel, staged ds_read2 fetch ----
            const float4 tvs[4] = {tvp[0], tvp[180], tvp[360], tvp[540]};
            const float pX[4] = {X, Y, -X, -Y};
            const float pY[4] = {Y, -X, -Y, X};
            float* accp[4] = {&acc0, &acc1, &acc2, &acc3};
            #pragma unroll
            for (int j = 0; j < 4; ++j) {
                float Xm = pX[j], Ym = pY[j];
                #pragma unroll
                for (int k = 0; k < 4; ++k) {
                    const float4 tv = tvs[k];
                    float t2 = fmaf(tv.x, Xm, tv.y * Ym);               // R3-exact
                    float D  = fmaf(tv.w, Xm, fmaf(tv.z, -Ym, 595.0f)); // R3-exact
                    float rD = __builtin_amdgcn_rcpf(D);
                    float fidx = fmaf(t2, rD, 367.5f);
                    int i0c = min(max((int)fidx, 0), NU - 2);           // v_med3_i32
                    float f = __builtin_amdgcn_fractf(fidx);
                    const float* pe = winf + 4 * i0c;
                    float q0 = pe[k];                                   // ds_read2
                    float q1 = pe[k + 4];
                    float val = fmaf(f, q1 - q0, q0);
                    float cen = fidx - 367.5f;                          // R3-exact gate
                    float g = (__builtin_fabsf(cen) <= 367.5f) ? rD * rD : 0.0f;
                    *accp[j] = fmaf(g, val, *accp[j]);
                }
            }
        }
        __builtin_amdgcn_s_setprio(0);
        rowp += 16 * 3072;
        tvp += 16;
    }
    const float SC = (float)(595.0 * 595.0 * 0.5 * (2.0 * M_PI / 720.0));
    const int ir = 511 - iq, jr = 511 - jq;
    unsafeAtomicAdd(&out[iq * NXY + jq], acc0 * SC);   // P0 = (iq, jq)
    unsafeAtomicAdd(&out[jq * NXY + ir], acc1 * SC);   // P1 = (jq, 511-iq)
    unsafeAtomicAdd(&out[ir * NXY + jr], acc2 * SC);   // P2 = (511-iq, 511-jq)
    unsafeAtomicAdd(&out[jr * NXY + iq], acc3 * SC);   // P3 = (511-jq, iq)
}

extern "C" void kernel_launch(void* const* d_in, const int* in_sizes, int n_in,
                              void* d_out, int out_size, void* d_ws, size_t ws_size,
                              hipStream_t stream) {
    const float* sino = (const float*)d_in[0];
    float* out = (float*)d_out;
    float* Qi = (float*)d_ws;                               // 180*3072*4 = 2,211,840 B
    float4* trig = (float4*)((char*)d_ws + (size_t)180 * 3072 * sizeof(float));

    filter_kernel<<<720, 512, 0, stream>>>(sino, Qi, trig, out);   // also zeroes out
    bp_kernel<<<4096, 256, 0, stream>>>(Qi, trig, out);
}